// Round 9
// baseline (162.127 us; speedup 1.0000x reference)
//
#include <hip/hip_runtime.h>
#include <hip/hip_bf16.h>
#include <math.h>

// ---------------------------------------------------------------------------
// MoE gate via fp16 hi/lo split MFMA, 3 products (validated round 5):
//   x = xh + xl/2048,  W*64 = wh + wl/2048
//   logit = ( xh·wh + (xh·wl + xl·wh)/2048 ) / 64
// Round 9: m201-style 4-phase schedule with counted vmcnt (T3+T4+T5).
// 512 thr / 8 waves (2Mx4N), BM=128, BN=256 (X read once), BK=32, dbuf
// 2x48KB. Per tile: 4 phases {ds_read || stage-issue, SBAR, lgkm(0),
// setprio+12 MFMA, SBAR}; tile-end s_waitcnt vmcnt(2) lgkmcnt(0) keeps the
// 2 A-prefetch loads in flight across the barrier (never drain to 0).
// Numerics / routing / fp64 KS-combine identical to rounds 5-8 (passed).
// ---------------------------------------------------------------------------

typedef _Float16 f16x8 __attribute__((ext_vector_type(8)));
typedef float    f32x4 __attribute__((ext_vector_type(4)));

__device__ __forceinline__ void glds16(const void* g, void* l) {
  __builtin_amdgcn_global_load_lds(
      (const __attribute__((address_space(1))) void*)g,
      (__attribute__((address_space(3))) void*)l, 16, 0, 0);
}

__device__ __forceinline__ unsigned short f2h(float f) {
  _Float16 h = (_Float16)f;                       // v_cvt_f16_f32, RTN
  return __builtin_bit_cast(unsigned short, h);
}
__device__ __forceinline__ float h2f(unsigned short b) {
  return (float)__builtin_bit_cast(_Float16, b);
}

// swizzle for 64B rows (4 granules of 16B), bijective in gi per row.
__device__ __forceinline__ int swz(int gi, int row) {
  return gi ^ (row & 3) ^ ((row >> 2) & 3);
}

// ---------------------------------------------------------------------------
// W [256][7168] fp32 -> Whi/Wlo fp16, tiled pre-swizzled layout (BK=32):
// K-tile t in 0..223 = 256 rows x 32 f16 = 8192 ushorts (16KB).
// element (r,k): gi=k>>3, addr = t*8192 + r*32 + swz(gi,r)*8 + (k&7).
// Whi = fp16(64*W); Wlo = fp16((64*W - Whi) * 2048).
// ---------------------------------------------------------------------------
__global__ __launch_bounds__(256) void convert_w(
    const float* __restrict__ W,
    unsigned short* __restrict__ Whi, unsigned short* __restrict__ Wlo)
{
  const int e = blockIdx.x;           // expert/row 0..255
  const int t = threadIdx.x;          // 0..255, use 224 (one K-tile each)
  if (t >= 224) return;
  const float* src = W + (size_t)e * 7168 + t * 32;
  const size_t tbase = (size_t)t * 8192 + (size_t)e * 32;
  #pragma unroll
  for (int g = 0; g < 4; ++g) {       // granule gi = g, k = g*8..g*8+7
    unsigned int hw[4], lw[4];
    #pragma unroll
    for (int p = 0; p < 4; ++p) {
      float f0 = src[g * 8 + 2 * p] * 64.0f;
      float f1 = src[g * 8 + 2 * p + 1] * 64.0f;
      unsigned short h0 = f2h(f0), h1 = f2h(f1);
      unsigned short l0 = f2h((f0 - h2f(h0)) * 2048.0f);
      unsigned short l1 = f2h((f1 - h2f(h1)) * 2048.0f);
      hw[p] = (unsigned)h0 | ((unsigned)h1 << 16);
      lw[p] = (unsigned)l0 | ((unsigned)l1 << 16);
    }
    const size_t base = tbase + (size_t)(swz(g, e) * 8);
    *(uint4*)(Whi + base) = make_uint4(hw[0], hw[1], hw[2], hw[3]);
    *(uint4*)(Wlo + base) = make_uint4(lw[0], lw[1], lw[2], lw[3]);
  }
}

// LDS buffer layout (per 48KB buffer):
//   Ahi +0 (8KB, 128 rows x 64B) | Alo +8192 | Bhi +16384 (16KB, 256x64B) |
//   Blo +32768.  Two buffers: 0 and 49152.
#define BUF_SZ   49152
#define A_LO_OFF 8192
#define B_HI_OFF 16384
#define B_LO_OFF 32768

__device__ __forceinline__ void conv_pack8(const float4& a0, const float4& a1,
                                           uint4& hv, uint4& lv) {
  float ff[8] = {a0.x, a0.y, a0.z, a0.w, a1.x, a1.y, a1.z, a1.w};
  unsigned int hw[4], lw[4];
  #pragma unroll
  for (int q = 0; q < 4; ++q) {
    float f0 = ff[2 * q], f1 = ff[2 * q + 1];
    unsigned short h0 = f2h(f0), h1 = f2h(f1);
    unsigned short l0 = f2h((f0 - h2f(h0)) * 2048.0f);
    unsigned short l1 = f2h((f1 - h2f(h1)) * 2048.0f);
    hw[q] = (unsigned)h0 | ((unsigned)h1 << 16);
    lw[q] = (unsigned)l0 | ((unsigned)l1 << 16);
  }
  hv = make_uint4(hw[0], hw[1], hw[2], hw[3]);
  lv = make_uint4(lw[0], lw[1], lw[2], lw[3]);
}

// ---------------------------------------------------------------------------
// GEMM: BM=128, BN=256, BK=32, K-split KS. 512 threads = 8 waves (2Mx4N),
// wave tile 64x64 = 4x4 frags of 16x16x32 f16 MFMA, 3 products.
// ---------------------------------------------------------------------------
__global__ __launch_bounds__(512, 2) void gate_gemm(
    const float* __restrict__ X,
    const unsigned short* __restrict__ Whi,
    const unsigned short* __restrict__ Wlo,
    float* __restrict__ Spart, int D, int TILES, int KS)
{
  __shared__ char lds[98304];

  const int bid = blockIdx.x;
  const int ks = bid % KS;
  const int bm = bid / KS;
  const int tid = threadIdx.x, lane = tid & 63, wid = tid >> 6;
  const int wm = wid >> 2, wn = wid & 3;     // 2x4 wave grid
  const int TM = bm * 128;
  const int k0base = ks * TILES * 32;

  // A staging: 4 threads per row, 8 contiguous fp32 (one granule pair... 8=gran)
  const int srow = tid >> 2, sg = tid & 3;
  const float* xsrc = X + (size_t)(TM + srow) * D + k0base + sg * 8;
  const int awA = srow * 64 + swz(sg, srow) * 16;   // byte offset in A region

  const unsigned short* wh_tile = Whi + (size_t)(ks * TILES) * 8192;
  const unsigned short* wl_tile = Wlo + (size_t)(ks * TILES) * 8192;

  f32x4 acc1[4][4], acc2[4][4];
  #pragma unroll
  for (int m = 0; m < 4; ++m)
    #pragma unroll
    for (int n = 0; n < 4; ++n) { acc1[m][n] = (f32x4)0.0f; acc2[m][n] = (f32x4)0.0f; }

  // fragment read byte offsets, fixed per lane
  int aro[4], bro[4];
  const int gi = lane >> 4;
  #pragma unroll
  for (int m = 0; m < 4; ++m) {
    const int row = wm * 64 + m * 16 + (lane & 15);
    aro[m] = row * 64 + swz(gi, row) * 16;
  }
  #pragma unroll
  for (int n = 0; n < 4; ++n) {
    const int row = wn * 64 + n * 16 + (lane & 15);
    bro[n] = row * 64 + swz(gi, row) * 16;
  }

  // ---- prologue: stage tile 0 into buf0; prefetch A(1) ----
  float4 pa0, pa1, pb0, pb1;
  {
    // B(0) hi+lo: 4 glds per thread (wave wid stages chunks 2w,2w+1)
    #pragma unroll
    for (int i = 0; i < 2; ++i) {
      const int c = wid * 2 + i;
      glds16(wh_tile + c * 512 + lane * 8, lds + B_HI_OFF + c * 1024);
      glds16(wl_tile + c * 512 + lane * 8, lds + B_LO_OFF + c * 1024);
    }
    __builtin_amdgcn_sched_barrier(0);
    // A(0): load + convert + ds_write
    float4 a0 = *(const float4*)(xsrc);
    float4 a1 = *(const float4*)(xsrc + 4);
    uint4 hv, lv;
    conv_pack8(a0, a1, hv, lv);
    *(uint4*)(lds + awA)            = hv;
    *(uint4*)(lds + A_LO_OFF + awA) = lv;
    // prefetch A(1)
    const int s1 = (TILES > 1) ? 1 : 0;
    pa0 = *(const float4*)(xsrc + (size_t)s1 * 32);
    pa1 = *(const float4*)(xsrc + (size_t)s1 * 32 + 4);
    __builtin_amdgcn_sched_barrier(0);
  }
  asm volatile("s_waitcnt vmcnt(2) lgkmcnt(0)" ::: "memory");
  __builtin_amdgcn_sched_barrier(0);
  __builtin_amdgcn_s_barrier();

  int cur = 0;
  for (int s = 0; s < TILES; ++s) {
    char* base_c = lds + cur * BUF_SZ;
    char* base_n = lds + (cur ^ 1) * BUF_SZ;
    const bool stage_next = (s + 1 < TILES);

    f16x8 ah[4], al[4];

    // ---------------- phase 0: A frags + B0; stage B(s+1) hi ----------------
    f16x8 bh0, bl0;
    #pragma unroll
    for (int m = 0; m < 4; ++m) {
      ah[m] = *(const f16x8*)(base_c + aro[m]);
      al[m] = *(const f16x8*)(base_c + A_LO_OFF + aro[m]);
    }
    bh0 = *(const f16x8*)(base_c + B_HI_OFF + bro[0]);
    bl0 = *(const f16x8*)(base_c + B_LO_OFF + bro[0]);
    if (stage_next) {
      const unsigned short* wh = wh_tile + (size_t)(s + 1) * 8192;
      #pragma unroll
      for (int i = 0; i < 2; ++i) {
        const int c = wid * 2 + i;
        glds16(wh + c * 512 + lane * 8, base_n + B_HI_OFF + c * 1024);
      }
    }
    __builtin_amdgcn_sched_barrier(0);
    __builtin_amdgcn_s_barrier();
    asm volatile("s_waitcnt lgkmcnt(0)" ::: "memory");
    __builtin_amdgcn_sched_barrier(0);
    __builtin_amdgcn_s_setprio(1);
    #pragma unroll
    for (int m = 0; m < 4; ++m)
      acc1[m][0] = __builtin_amdgcn_mfma_f32_16x16x32_f16(ah[m], bh0, acc1[m][0], 0, 0, 0);
    #pragma unroll
    for (int m = 0; m < 4; ++m)
      acc2[m][0] = __builtin_amdgcn_mfma_f32_16x16x32_f16(ah[m], bl0, acc2[m][0], 0, 0, 0);
    #pragma unroll
    for (int m = 0; m < 4; ++m)
      acc2[m][0] = __builtin_amdgcn_mfma_f32_16x16x32_f16(al[m], bh0, acc2[m][0], 0, 0, 0);
    __builtin_amdgcn_s_setprio(0);
    __builtin_amdgcn_s_barrier();

    // ---------------- phase 1: B1; stage B(s+1) lo; prefetch A(s+2) --------
    f16x8 bh1, bl1;
    bh1 = *(const f16x8*)(base_c + B_HI_OFF + bro[1]);
    bl1 = *(const f16x8*)(base_c + B_LO_OFF + bro[1]);
    if (stage_next) {
      const unsigned short* wl = wl_tile + (size_t)(s + 1) * 8192;
      #pragma unroll
      for (int i = 0; i < 2; ++i) {
        const int c = wid * 2 + i;
        glds16(wl + c * 512 + lane * 8, base_n + B_LO_OFF + c * 1024);
      }
    }
    __builtin_amdgcn_sched_barrier(0);
    {
      int sn = s + 2; if (sn > TILES - 1) sn = TILES - 1;   // clamp: always 2 in flight
      pb0 = *(const float4*)(xsrc + (size_t)sn * 32);
      pb1 = *(const float4*)(xsrc + (size_t)sn * 32 + 4);
    }
    __builtin_amdgcn_sched_barrier(0);
    __builtin_amdgcn_s_barrier();
    asm volatile("s_waitcnt lgkmcnt(0)" ::: "memory");
    __builtin_amdgcn_sched_barrier(0);
    __builtin_amdgcn_s_setprio(1);
    #pragma unroll
    for (int m = 0; m < 4; ++m)
      acc1[m][1] = __builtin_amdgcn_mfma_f32_16x16x32_f16(ah[m], bh1, acc1[m][1], 0, 0, 0);
    #pragma unroll
    for (int m = 0; m < 4; ++m)
      acc2[m][1] = __builtin_amdgcn_mfma_f32_16x16x32_f16(ah[m], bl1, acc2[m][1], 0, 0, 0);
    #pragma unroll
    for (int m = 0; m < 4; ++m)
      acc2[m][1] = __builtin_amdgcn_mfma_f32_16x16x32_f16(al[m], bh1, acc2[m][1], 0, 0, 0);
    __builtin_amdgcn_s_setprio(0);
    __builtin_amdgcn_s_barrier();

    // ---------------- phase 2: B2; convert+ds_write A(s+1) -----------------
    f16x8 bh2, bl2;
    bh2 = *(const f16x8*)(base_c + B_HI_OFF + bro[2]);
    bl2 = *(const f16x8*)(base_c + B_LO_OFF + bro[2]);
    if (stage_next) {
      uint4 hv, lv;
      conv_pack8(pa0, pa1, hv, lv);
      *(uint4*)(base_n + awA)            = hv;
      *(uint4*)(base_n + A_LO_OFF + awA) = lv;
    }
    __builtin_amdgcn_sched_barrier(0);
    __builtin_amdgcn_s_barrier();
    asm volatile("s_waitcnt lgkmcnt(0)" ::: "memory");
    __builtin_amdgcn_sched_barrier(0);
    __builtin_amdgcn_s_setprio(1);
    #pragma unroll
    for (int m = 0; m < 4; ++m)
      acc1[m][2] = __builtin_amdgcn_mfma_f32_16x16x32_f16(ah[m], bh2, acc1[m][2], 0, 0, 0);
    #pragma unroll
    for (int m = 0; m < 4; ++m)
      acc2[m][2] = __builtin_amdgcn_mfma_f32_16x16x32_f16(ah[m], bl2, acc2[m][2], 0, 0, 0);
    #pragma unroll
    for (int m = 0; m < 4; ++m)
      acc2[m][2] = __builtin_amdgcn_mfma_f32_16x16x32_f16(al[m], bh2, acc2[m][2], 0, 0, 0);
    __builtin_amdgcn_s_setprio(0);
    __builtin_amdgcn_s_barrier();

    // ---------------- phase 3: B3; MFMA; tile-end counted drain ------------
    f16x8 bh3, bl3;
    bh3 = *(const f16x8*)(base_c + B_HI_OFF + bro[3]);
    bl3 = *(const f16x8*)(base_c + B_LO_OFF + bro[3]);
    pa0 = pb0; pa1 = pb1;
    __builtin_amdgcn_s_barrier();
    asm volatile("s_waitcnt lgkmcnt(0)" ::: "memory");
    __builtin_amdgcn_sched_barrier(0);
    __builtin_amdgcn_s_setprio(1);
    #pragma unroll
    for (int m = 0; m < 4; ++m)
      acc1[m][3] = __builtin_amdgcn_mfma_f32_16x16x32_f16(ah[m], bh3, acc1[m][3], 0, 0, 0);
    #pragma unroll
    for (int m = 0; m < 4; ++m)
      acc2[m][3] = __builtin_amdgcn_mfma_f32_16x16x32_f16(ah[m], bl3, acc2[m][3], 0, 0, 0);
    #pragma unroll
    for (int m = 0; m < 4; ++m)
      acc2[m][3] = __builtin_amdgcn_mfma_f32_16x16x32_f16(al[m], bh3, acc2[m][3], 0, 0, 0);
    __builtin_amdgcn_s_setprio(0);
    // counted drain: 4 glds (oldest) must be done; 2 A-prefetch loads stay
    asm volatile("s_waitcnt vmcnt(2) lgkmcnt(0)" ::: "memory");
    __builtin_amdgcn_sched_barrier(0);
    __builtin_amdgcn_s_barrier();

    cur ^= 1;
  }

  // epilogue: logit partial = (acc1 + acc2/2048) / 64
  // C/D layout: col=lane&15, row=(lane>>4)*4+reg
  float* Sp = Spart + (size_t)ks * 8192 * 256;
  #pragma unroll
  for (int m = 0; m < 4; ++m)
    #pragma unroll
    for (int n = 0; n < 4; ++n)
      #pragma unroll
      for (int r = 0; r < 4; ++r) {
        const int t = TM + wm * 64 + m * 16 + (lane >> 4) * 4 + r;
        const int e = wn * 64 + n * 16 + (lane & 15);
        Sp[(size_t)t * 256 + e] =
            (acc1[m][n][r] + acc2[m][n][r] * (1.0f / 2048.0f)) * (1.0f / 64.0f);
      }
}

// ---------------------------------------------------------------------------
// Routing: one wave per token. logit = sum of KS fp32 partials in DOUBLE
// (exact); scores = sigmoid (fp32); then grouped top-k (8 groups, top-2
// group score, top-4 groups, top-8 experts, renorm * 2.5).
// ---------------------------------------------------------------------------
__global__ __launch_bounds__(256) void gate_routing(
    const float* __restrict__ Spart, int KS,
    const float* __restrict__ bias,
    float* __restrict__ outw, float* __restrict__ outi, int T)
{
  const int lane = threadIdx.x & 63;
  const int wave = threadIdx.x >> 6;
  const int t = blockIdx.x * 4 + wave;
  if (t >= T) return;

  double l[4] = {0.0, 0.0, 0.0, 0.0};
  for (int ks = 0; ks < KS; ++ks) {
    float4 p = *(const float4*)(Spart + (size_t)ks * T * 256
                                + (size_t)t * 256 + lane * 4);
    l[0] += (double)p.x; l[1] += (double)p.y;
    l[2] += (double)p.z; l[3] += (double)p.w;
  }

  float4 bi = *(const float4*)(bias + lane * 4);
  float orig[4], s[4];
  #pragma unroll
  for (int u = 0; u < 4; ++u)
    orig[u] = 1.0f / (1.0f + expf(-(float)l[u]));
  s[0] = orig[0] + bi.x; s[1] = orig[1] + bi.y;
  s[2] = orig[2] + bi.z; s[3] = orig[3] + bi.w;

  // per-lane top-2 of its 4 biased scores
  float m1 = -INFINITY, m2 = -INFINITY;
  #pragma unroll
  for (int u = 0; u < 4; ++u) {
    float v = s[u];
    if (v > m1) { m2 = m1; m1 = v; }
    else if (v > m2) { m2 = v; }
  }
  // merge top-2 across the 8 lanes of the group
  #pragma unroll
  for (int off = 1; off < 8; off <<= 1) {
    float o1 = __shfl_xor(m1, off, 64);
    float o2 = __shfl_xor(m2, off, 64);
    if (o1 > m1) { m2 = fmaxf(m1, o2); m1 = o1; }
    else         { m2 = fmaxf(m2, o1); }
  }
  const float gscore = m1 + m2;

  const int g = lane >> 3;
  int rank = 0;
  #pragma unroll
  for (int j = 0; j < 8; ++j) {
    float gs = __shfl(gscore, j * 8, 64);
    rank += (gs > gscore || (gs == gscore && j < g)) ? 1 : 0;
  }
  if (rank >= 4) { s[0] = s[1] = s[2] = s[3] = -INFINITY; }

  float wsum = 0.0f, sel_w = 0.0f;
  int sel_i = 0;
  #pragma unroll
  for (int it = 0; it < 8; ++it) {
    float bv = s[0]; int bu = 0;
    #pragma unroll
    for (int u = 1; u < 4; ++u)
      if (s[u] > bv) { bv = s[u]; bu = u; }
    float v = bv;
    int ix = lane * 4 + bu;
    float og = orig[bu];
    #pragma unroll
    for (int off = 1; off < 64; off <<= 1) {
      float ov  = __shfl_xor(v,  off, 64);
      int   oix = __shfl_xor(ix, off, 64);
      float oog = __shfl_xor(og, off, 64);
      if (ov > v || (ov == v && oix < ix)) { v = ov; ix = oix; og = oog; }
    }
    if (lane == it) { sel_w = og; sel_i = ix; }
    wsum += og;
    if ((ix >> 2) == lane) s[ix & 3] = -INFINITY;
  }

  if (lane < 8) {
    outw[(size_t)t * 8 + lane] = sel_w / wsum * 2.5f;
    outi[(size_t)t * 8 + lane] = (float)sel_i;
  }
}

extern "C" void kernel_launch(void* const* d_in, const int* in_sizes, int n_in,
                              void* d_out, int out_size, void* d_ws, size_t ws_size,
                              hipStream_t stream) {
  const float* x = (const float*)d_in[0];
  const float* w = (const float*)d_in[1];
  const float* b = (const float*)d_in[2];
  const int E = in_sizes[2];                  // 256
  const int D = in_sizes[1] / E;              // 7168
  const int T = in_sizes[0] / D;              // 8192

  unsigned short* Whi = (unsigned short*)d_ws;                       // 3.67 MB
  unsigned short* Wlo = (unsigned short*)((char*)d_ws + (4u << 20)); // 3.67 MB
  float* Spart = (float*)((char*)d_ws + (8u << 20));                 // KS x 8 MB

  // adaptive K-split: largest of {8,4,2} that fits the workspace
  const size_t per_part = (size_t)T * E * 4;
  int KS = 2;
  if (ws_size >= (8u << 20) + 8 * per_part) KS = 8;
  else if (ws_size >= (8u << 20) + 4 * per_part) KS = 4;
  const int TILES = D / (32 * KS);            // 28 for KS=8

  float* outw = (float*)d_out;
  float* outi = outw + (size_t)T * 8;

  convert_w<<<E, 256, 0, stream>>>(w, Whi, Wlo);
  // grid: (T/128) x KS, ks fastest (XCD-affine for KS=8)
  gate_gemm<<<(T / 128) * KS, 512, 0, stream>>>(x, Whi, Wlo, Spart, D, TILES, KS);
  gate_routing<<<(T + 3) / 4, 256, 0, stream>>>(Spart, KS, b, outw, outi, T);
}